// Round 6
// baseline (338.013 us; speedup 1.0000x reference)
//
#include <hip/hip_runtime.h>
#include <stdint.h>
#include <math.h>

typedef unsigned short u16;
typedef __attribute__((ext_vector_type(8))) short short8;
typedef __attribute__((ext_vector_type(8))) u16 ushort8;
typedef __attribute__((ext_vector_type(4))) u16 u16x4;
typedef __attribute__((ext_vector_type(4))) float floatx4;

__device__ __forceinline__ u16 f2bf(float f) {
  union { float f; unsigned u; } c; c.f = f;
  unsigned u = c.u;
  return (u16)((u + 0x7fffu + ((u >> 16) & 1u)) >> 16);
}
__device__ __forceinline__ float bf2f(u16 h) {
  union { unsigned u; float f; } c; c.u = (unsigned)h << 16;
  return c.f;
}

// async global->LDS, 16 bytes per lane; LDS dest must be lane-contiguous.
__device__ __forceinline__ void async16(const u16* g, u16* l) {
  auto* gp = reinterpret_cast<const __attribute__((address_space(1))) uint32_t*>(
      reinterpret_cast<uintptr_t>(g));
  auto* lp = reinterpret_cast<__attribute__((address_space(3))) uint32_t*>(
      reinterpret_cast<uintptr_t>(l));
  __builtin_amdgcn_global_load_lds(gp, lp, 16, 0, 0);
}

// ---------------------------------------------------------------------------
// C = A * B^T.  A: [M][K] bf16 row-major (lda), B: [N][K] bf16 row-major (ldb).
// NW waves (NW*64 threads). NW=4: 128x128 tile; NW=2: 128x64 tile.
// Wave tile is always 64x64 (16 MFMA : 8 ds_read_b128 per K-step).
// Double-buffered LDS + vmcnt(NLOAD) pipeline: tile k+1's global_load_lds stays
// in flight across a raw s_barrier while tile k computes.
// LDS XOR swizzle: 16B seg s of row r at phys seg s^((r>>1)&3) -> conflict-free
// (row-block strides are multiples of 32 so the mask is round-invariant).
// tri_grid (NW=2): blockIdx.x enumerates lower-triangle 128x64 tiles.
// rev_m: reverse m-order so heavy causal_klimit blocks launch first.
// vpt: z==2 writes C transposed as [4][1024][2048] (vp^T direct).
// TAG only differentiates symbols for rocprof attribution.
// ---------------------------------------------------------------------------
template <int TAG, int NW, int OUT_BF16>
__global__ __launch_bounds__(NW * 64) void gemm_bt(
    const u16* __restrict__ A, const u16* __restrict__ B, void* __restrict__ Cv,
    int K, int lda, int ldb, int ldc,
    long long sA, long long sB, long long sC,
    float scale, int tri_grid, int causal_klimit, int rev_m,
    int vpt, u16* __restrict__ vpC) {
  constexpr int BN = (NW == 4) ? 128 : 64;
  constexpr int RPR = NW * 16;    // rows staged per issue round
  constexpr int AR = 128 / RPR;   // A issue rounds
  constexpr int BR = BN / RPR;    // B issue rounds
  constexpr int NLOAD = AR + BR;  // staging loads per thread per K-step
  constexpr int WAIT_KT = 0xF70 | NLOAD;  // vmcnt(NLOAD), lgkm/exp don't-care
  constexpr int WAIT_0 = 0xF70;           // vmcnt(0)

  int bm, bn;
  if (tri_grid) {
    // rows of width (bm*128+128)/BN tiles; prefix for BN=64: bm*(bm+1)
    const int bx = blockIdx.x;
    int i = (int)sqrtf((float)bx);
    while ((i + 1) * (i + 2) <= bx) ++i;
    while (i * (i + 1) > bx) --i;
    bm = i;
    bn = bx - i * (i + 1);
  } else {
    bm = rev_m ? ((int)gridDim.x - 1 - (int)blockIdx.x) : (int)blockIdx.x;
    bn = blockIdx.y;
  }
  const int m0 = bm * 128;
  const int n0 = bn * BN;
  A += (size_t)blockIdx.z * sA;
  B += (size_t)blockIdx.z * sB;

  __shared__ u16 As[2][4096];
  __shared__ u16 Bs[2][BN * 32];

  const int tid = threadIdx.x;
  const int lane = tid & 63;
  const int wid = tid >> 6;
  const int wm = (wid & 1) * 64;
  const int wn = (wid >> 1) * 64;
  const int fr = lane & 15;   // m/n within 16x16 frag
  const int fq = lane >> 4;   // logical k-segment

  floatx4 acc[4][4] = {};

  int kt_end = K >> 5;
  if (causal_klimit) {
    int lim = (m0 >> 5) + 4;
    if (lim < kt_end) kt_end = lim;
  }

  const int rowi = tid >> 2;                 // 0..RPR*4/4-1
  const int segi = tid & 3;                  // physical 16B seg
  const int sgz = segi ^ ((rowi >> 1) & 3);  // logical seg to fetch
  const u16* gA = A + (size_t)(m0 + rowi) * lda + sgz * 8;
  const u16* gB = B + (size_t)(n0 + rowi) * ldb + sgz * 8;

  // fragment read offsets (swizzled), within one buffer
  int offA[4], offB[4];
#pragma unroll
  for (int i = 0; i < 4; ++i) {
    int ra = wm + i * 16 + fr;
    offA[i] = ra * 32 + (fq ^ ((ra >> 1) & 3)) * 8;
    int rb = wn + i * 16 + fr;
    offB[i] = rb * 32 + (fq ^ ((rb >> 1) & 3)) * 8;
  }

  auto issue = [&](int kt) {
    const int k0 = kt << 5;
    const int odd = kt & 1;
#pragma unroll
    for (int r = 0; r < AR; ++r)
      async16(gA + k0 + (size_t)(r * RPR) * lda,
              &As[odd][tid * 8 + r * RPR * 32]);
#pragma unroll
    for (int r = 0; r < BR; ++r)
      async16(gB + k0 + (size_t)(r * RPR) * ldb,
              &Bs[odd][tid * 8 + r * RPR * 32]);
  };

  issue(0);
  for (int kt = 0; kt < kt_end; ++kt) {
    if (kt + 1 < kt_end) {
      issue(kt + 1);
      __builtin_amdgcn_s_waitcnt(WAIT_KT);  // tile kt's loads retired
    } else {
      __builtin_amdgcn_s_waitcnt(WAIT_0);
    }
    asm volatile("s_barrier" ::: "memory");

    const u16* ab = As[kt & 1];
    const u16* bb = Bs[kt & 1];
    short8 av[4], bv[4];
#pragma unroll
    for (int i = 0; i < 4; ++i) av[i] = *(const short8*)(ab + offA[i]);
#pragma unroll
    for (int j = 0; j < 4; ++j) bv[j] = *(const short8*)(bb + offB[j]);

#pragma unroll
    for (int i = 0; i < 4; ++i)
#pragma unroll
      for (int j = 0; j < 4; ++j)
        acc[i][j] = __builtin_amdgcn_mfma_f32_16x16x32_bf16(av[i], bv[j],
                                                            acc[i][j], 0, 0, 0);
    asm volatile("s_barrier" ::: "memory");  // readers done before overwrite
  }

  // Epilogue. C/D layout: col = lane&15 (=fr), row = fq*4 + reg.
  if (vpt && blockIdx.z == 2) {
    // write transposed: vpC[b][n][t], b = m>>11, t = m&2047 (T=2048, H=1024)
#pragma unroll
    for (int i = 0; i < 4; ++i) {
      const int m = m0 + wm + i * 16 + fq * 4;
      const int b = m >> 11, t = m & 2047;
#pragma unroll
      for (int j = 0; j < 4; ++j) {
        const int n = n0 + wn + j * 16 + fr;
        u16x4 o;
#pragma unroll
        for (int r = 0; r < 4; ++r) o[r] = f2bf(acc[i][j][r]);
        *(u16x4*)&vpC[(size_t)b * 2097152 + (size_t)n * 2048 + t] = o;
      }
    }
    return;
  }
  if (OUT_BF16) {
    u16* C = (u16*)Cv + (size_t)blockIdx.z * sC;
#pragma unroll
    for (int i = 0; i < 4; ++i) {
      const int m = m0 + wm + i * 16 + fq * 4;
#pragma unroll
      for (int j = 0; j < 4; ++j) {
        const int n = n0 + wn + j * 16 + fr;
#pragma unroll
        for (int r = 0; r < 4; ++r)
          C[(size_t)(m + r) * ldc + n] = f2bf(acc[i][j][r] * scale);
      }
    }
  } else {
    float* C = (float*)Cv + (size_t)blockIdx.z * sC;
#pragma unroll
    for (int i = 0; i < 4; ++i) {
      const int m = m0 + wm + i * 16 + fq * 4;
#pragma unroll
      for (int j = 0; j < 4; ++j) {
        const int n = n0 + wn + j * 16 + fr;
#pragma unroll
        for (int r = 0; r < 4; ++r)
          C[(size_t)(m + r) * ldc + n] = acc[i][j][r] * scale;
      }
    }
  }
}

// fp32 -> bf16 cast for q,k,v in one dispatch (blockIdx.y selects source)
__global__ __launch_bounds__(256) void cast3(
    const float* __restrict__ q, const float* __restrict__ k,
    const float* __restrict__ v, u16* __restrict__ out, int n8) {
  int i = blockIdx.x * 256 + threadIdx.x;
  if (i >= n8) return;
  const float* src = blockIdx.y == 0 ? q : (blockIdx.y == 1 ? k : v);
  u16* dst = out + (size_t)blockIdx.y * n8 * 8;
  floatx4 a = ((const floatx4*)src)[i * 2];
  floatx4 b = ((const floatx4*)src)[i * 2 + 1];
  ushort8 o;
#pragma unroll
  for (int j = 0; j < 4; ++j) { o[j] = f2bf(a[j]); o[4 + j] = f2bf(b[j]); }
  ((ushort8*)dst)[i] = o;
}

// fp32 [R][C] -> bf16 [C][R] transpose+cast, 64x64 tiles; z picks (Wq,Wk,Wq)
__global__ __launch_bounds__(256) void transpose_castW(
    const float* __restrict__ Wq, const float* __restrict__ Wk,
    u16* __restrict__ out, int R, int C) {
  __shared__ u16 tile[64][72];
  const float* in = (blockIdx.z == 1) ? Wk : Wq;
  u16* dst = out + (size_t)blockIdx.z * R * C;
  const int r0 = blockIdx.x * 64;
  const int c0 = blockIdx.y * 64;
  const int tid = threadIdx.x;
#pragma unroll
  for (int rnd = 0; rnd < 2; ++rnd) {
    int e = rnd * 256 + tid;
    int rr = e >> 3, seg = e & 7;
    const float* p = &in[(size_t)(r0 + rr) * C + c0 + seg * 8];
    floatx4 a = *(const floatx4*)p;
    floatx4 b = *(const floatx4*)(p + 4);
    u16* tp = &tile[rr][seg * 8];
#pragma unroll
    for (int j = 0; j < 4; ++j) { tp[j] = f2bf(a[j]); tp[4 + j] = f2bf(b[j]); }
  }
  __syncthreads();
#pragma unroll
  for (int rnd = 0; rnd < 2; ++rnd) {
    int e = rnd * 256 + tid;
    int cc = e >> 3, rseg = e & 7;
    ushort8 tv;
#pragma unroll
    for (int j = 0; j < 8; ++j) tv[j] = tile[rseg * 8 + j][cc];
    *(ushort8*)&dst[(size_t)(c0 + cc) * R + r0 + rseg * 8] = tv;
  }
}

// Causal row softmax, bf16 in-place, T=2048: each of 256 threads owns exactly
// one ushort8 (one vec read + one vec write). Reads all precede the reduction
// barriers; writes follow -> in-place safe.
__global__ __launch_bounds__(256) void softmax_causal(u16* __restrict__ S,
                                                      int T) {
  const int row = blockIdx.x;
  const int t = row & (T - 1);
  const int len = t + 1;
  u16* srow = S + (size_t)row * T;
  const int tid = threadIdx.x;
  const int base = tid * 8;

  ushort8 v8 = *(const ushort8*)&srow[base];
  float vals[8];
  float mx = -1e30f;
#pragma unroll
  for (int j = 0; j < 8; ++j) {
    float x = (base + j < len) ? bf2f(v8[j]) : -1e30f;
    vals[j] = x;
    mx = fmaxf(mx, x);
  }
  __shared__ float red[4];
#pragma unroll
  for (int o = 32; o > 0; o >>= 1) mx = fmaxf(mx, __shfl_down(mx, o, 64));
  if ((tid & 63) == 0) red[tid >> 6] = mx;
  __syncthreads();
  mx = fmaxf(fmaxf(red[0], red[1]), fmaxf(red[2], red[3]));
  __syncthreads();

  float sum = 0.f;
#pragma unroll
  for (int j = 0; j < 8; ++j) {
    float e = (base + j < len) ? __expf(vals[j] - mx) : 0.f;
    vals[j] = e;
    sum += e;
  }
#pragma unroll
  for (int o = 32; o > 0; o >>= 1) sum += __shfl_down(sum, o, 64);
  if ((tid & 63) == 0) red[tid >> 6] = sum;
  __syncthreads();
  sum = red[0] + red[1] + red[2] + red[3];
  const float inv = 1.f / sum;

  ushort8 o8;
#pragma unroll
  for (int j = 0; j < 8; ++j) o8[j] = f2bf(vals[j] * inv);
  *(ushort8*)&srow[base] = o8;
}

extern "C" void kernel_launch(void* const* d_in, const int* in_sizes, int n_in,
                              void* d_out, int out_size, void* d_ws,
                              size_t ws_size, hipStream_t stream) {
  (void)in_sizes; (void)n_in; (void)out_size; (void)ws_size;
  const float* k  = (const float*)d_in[1];
  const float* q  = (const float*)d_in[2];
  const float* v  = (const float*)d_in[3];
  const float* Wk = (const float*)d_in[4];
  const float* Wq = (const float*)d_in[5];
  float* out = (float*)d_out;

  const int B = 4, T = 2048, C = 1024, H = 1024;
  const int M = B * T;  // 8192
  const size_t MC = (size_t)M * C, CH = (size_t)C * H, MH = (size_t)M * H;

  u16* qkv  = (u16*)d_ws;        // 3 slots [M][C] bf16 (q,k,v)        50 MB
  u16* WT   = qkv + 3 * MC;      // 3 slots [H][C] bf16 (Wq,Wk,Wq)      6 MB
  u16* qkvp = WT + 3 * CH;       // slot0 qp, slot1 kp [M][H]          34 MB
  u16* vpT  = qkvp + 2 * MH;     // [B][H][T] bf16 (vp^T, direct)      17 MB
  u16* Sb   = vpT + MH;          // [B][T][T] bf16 (S, then P)       33.5 MB

  const int n8 = (int)(MC / 8);
  cast3<<<dim3(n8 / 256, 3), 256, 0, stream>>>(q, k, v, qkv, n8);
  transpose_castW<<<dim3(C / 64, H / 64, 3), 256, 0, stream>>>(Wq, Wk, WT, C, H);

  // qp = q*Wq, kp = k*Wk, vp^T = (v*Wq)^T  (one batched dispatch, z=0..2)
  gemm_bt<0, 4, 1><<<dim3(M / 128, H / 128, 3), 256, 0, stream>>>(
      qkv, WT, qkvp, C, C, C, H,
      (long long)MC, (long long)CH, (long long)MH, 1.f, 0, 0, 0, 1, vpT);

  // S = qp*kp^T / 32 (bf16 out), compact lower-triangle 128x64 grid
  gemm_bt<1, 2, 1><<<dim3(272, 1, B), 128, 0, stream>>>(
      qkvp, qkvp + MH, Sb, H, H, H, T,
      (long long)T * H, (long long)T * H, (long long)T * T,
      0.03125f, 1, 0, 0, 0, nullptr);

  softmax_causal<<<dim3(B * T), 256, 0, stream>>>(Sb, T);

  // out = P * vpT^T (K limited to m0+128: P zero above diagonal), heavy-first
  gemm_bt<2, 2, 0><<<dim3(T / 128, H / 64, B), 128, 0, stream>>>(
      Sb, vpT, out, T, T, T, H,
      (long long)T * T, (long long)H * T, (long long)T * H,
      1.f, 0, 1, 1, 0, nullptr);
}